// Round 1
// baseline (22499.547 us; speedup 1.0000x reference)
//
#include <hip/hip_runtime.h>
#include <cmath>

// Problem constants
#define Bc   64
#define Sc   512
#define Dc   256
#define Hc   512
#define OUTc 128

// Kernel config
#define NWG  256   // total workgroups (128 layer0 + 128 layer1)
#define NTHR 256   // threads per WG (4 waves)
#define NL0  128   // layer-0 WGs
#define JPW  4     // h-indices owned per WG
#define NROW 16    // 4 gates * JPW rows per WG
#define KMAX 1024  // max K (layer1: 512 input + 512 recurrent)

// ws layout (floats): [0..255] barrier (uints), then h buffers
// bytes: bar 1024B region at 0 (use offsets 4096B for h start)
#define H1_F_OFF 1024                    // float offset of h1 buffers (byte 4096)
#define H_BUF_FLOATS (2 * Bc * Hc)       // 65536 floats per layer (double buffer)
#define WS_BYTES (4096 + 2 * H_BUF_FLOATS * 4)  // 528384

__device__ __forceinline__ void grid_barrier(unsigned* bar) {
    __syncthreads();
    if (threadIdx.x == 0) {
        // make this WG's global stores visible device-wide (L2 writeback)
        __builtin_amdgcn_fence(__ATOMIC_RELEASE, "agent");
        unsigned g = __hip_atomic_load(&bar[64], __ATOMIC_ACQUIRE, __HIP_MEMORY_SCOPE_AGENT);
        unsigned a = __hip_atomic_fetch_add(&bar[0], 1u, __ATOMIC_ACQ_REL, __HIP_MEMORY_SCOPE_AGENT);
        if (a == NWG - 1u) {
            __hip_atomic_store(&bar[0], 0u, __ATOMIC_RELAXED, __HIP_MEMORY_SCOPE_AGENT);
            __hip_atomic_fetch_add(&bar[64], 1u, __ATOMIC_RELEASE, __HIP_MEMORY_SCOPE_AGENT);
        } else {
            while (__hip_atomic_load(&bar[64], __ATOMIC_RELAXED, __HIP_MEMORY_SCOPE_AGENT) == g) {
                __builtin_amdgcn_s_sleep(2);
            }
        }
        // invalidate caches so fresh h values are read
        __builtin_amdgcn_fence(__ATOMIC_ACQUIRE, "agent");
    }
    __syncthreads();
}

__device__ __forceinline__ float sigmoidf_fast(float v) {
    return 1.0f / (1.0f + __expf(-v));
}

extern "C" __global__ void __launch_bounds__(NTHR)
lstm_persist(const float* __restrict__ x,
             const float* __restrict__ Wih0, const float* __restrict__ Whh0,
             const float* __restrict__ bih0, const float* __restrict__ bhh0,
             const float* __restrict__ Wih1, const float* __restrict__ Whh1,
             const float* __restrict__ bih1, const float* __restrict__ bhh1,
             const float* __restrict__ fcw, const float* __restrict__ fcb,
             float* __restrict__ out, float* __restrict__ wsf)
{
    __shared__ float Wl[NROW * KMAX];      // 64 KB: weight slice, resident all steps
    __shared__ float red[2 * Bc * NROW];   // 8 KB: cross-wave K-partial reduction

    unsigned* bar = (unsigned*)wsf;
    float* h1buf = wsf + H1_F_OFF;             // [2][B][H]
    float* h2buf = h1buf + H_BUF_FLOATS;       // [2][B][H]

    const int wg  = blockIdx.x;
    const int tid = threadIdx.x;
    const bool isL1 = (wg >= NL0);
    const int j0 = (isL1 ? wg - NL0 : wg) * JPW;
    const int K  = isL1 ? 1024 : 768;   // L0: 256 (x) + 512 (h1) ; L1: 512 (h1) + 512 (h2)
    const int KD = isL1 ? 512  : 256;   // boundary input-part / recurrent-part

    // ---- one-time: stage this WG's 16 gate rows (W_ih || W_hh) into LDS ----
    {
        const float* Wi = isL1 ? Wih1 : Wih0;
        const float* Wh = isL1 ? Whh1 : Whh0;
        for (int r = 0; r < NROW; ++r) {
            const int g = r >> 2, jj = r & 3;
            const int row = g * Hc + j0 + jj;
            for (int c = tid; c < K; c += NTHR) {
                Wl[r * K + c] = (c < KD) ? Wi[row * KD + c] : Wh[row * Hc + (c - KD)];
            }
        }
    }
    __syncthreads();

    // ---- GEMM thread tiling: wave = K quarter; lane -> (4 batches, 4 rows) ----
    const int w     = tid >> 6;
    const int lane  = tid & 63;
    const int bbase = (lane & 15) * 4;
    const int rbase = (lane >> 4) * 4;
    const int KQ = K >> 2;
    const int k0 = w * KQ;

    const float* wrow0 = &Wl[(rbase + 0) * K];
    const float* wrow1 = &Wl[(rbase + 1) * K];
    const float* wrow2 = &Wl[(rbase + 2) * K];
    const float* wrow3 = &Wl[(rbase + 3) * K];

    // ---- cell-update thread mapping: tid -> (batch cb, local j cjj); c in reg ----
    const int cb  = tid & 63;
    const int cjj = tid >> 6;
    float cstate = 0.0f;
    float bias4[4];
    {
        const float* bi = isL1 ? bih1 : bih0;
        const float* bh = isL1 ? bhh1 : bhh0;
#pragma unroll
        for (int g = 0; g < 4; ++g)
            bias4[g] = bi[g * Hc + j0 + cjj] + bh[g * Hc + j0 + cjj];
    }

    // ---- pipelined scan: super-step s -> L0 computes h1[s], L1 computes h2[s-1] ----
    for (int s = 0; s <= Sc; ++s) {
        const bool active = isL1 ? (s >= 1) : (s < Sc);
        if (active) {
            const int t = isL1 ? (s - 1) : s;
            const float* vrec = isL1 ? (h2buf + (size_t)(s & 1) * Bc * Hc)          // h2[s-2]
                                     : (h1buf + (size_t)((s - 1) & 1) * Bc * Hc);   // h1[s-1]
            const float* vinp = isL1 ? (h1buf + (size_t)((s - 1) & 1) * Bc * Hc)    // h1[s-1]
                                     : x;                                            // x[:,t,:]
            const float* vinb[4];
            const float* vrecb[4];
#pragma unroll
            for (int bb = 0; bb < 4; ++bb) {
                const int b = bbase + bb;
                vinb[bb]  = isL1 ? (vinp + (size_t)b * Hc)
                                 : (vinp + (size_t)b * Sc * Dc + (size_t)t * Dc);
                vrecb[bb] = vrec + (size_t)b * Hc;
            }

            float acc[4][4];
#pragma unroll
            for (int i = 0; i < 4; ++i)
#pragma unroll
                for (int j = 0; j < 4; ++j) acc[i][j] = 0.0f;

            for (int k = k0; k < k0 + KQ; k += 4) {
                const float4 wv0 = *(const float4*)(wrow0 + k);
                const float4 wv1 = *(const float4*)(wrow1 + k);
                const float4 wv2 = *(const float4*)(wrow2 + k);
                const float4 wv3 = *(const float4*)(wrow3 + k);
                const bool inp = (k < KD);      // wave-uniform per chunk
                float4 vv[4];
#pragma unroll
                for (int bb = 0; bb < 4; ++bb) {
                    const float* src = inp ? (vinb[bb] + k) : (vrecb[bb] + (k - KD));
                    vv[bb] = *(const float4*)src;
                }
#pragma unroll
                for (int bb = 0; bb < 4; ++bb) {
                    acc[bb][0] += wv0.x*vv[bb].x + wv0.y*vv[bb].y + wv0.z*vv[bb].z + wv0.w*vv[bb].w;
                    acc[bb][1] += wv1.x*vv[bb].x + wv1.y*vv[bb].y + wv1.z*vv[bb].z + wv1.w*vv[bb].w;
                    acc[bb][2] += wv2.x*vv[bb].x + wv2.y*vv[bb].y + wv2.z*vv[bb].z + wv2.w*vv[bb].w;
                    acc[bb][3] += wv3.x*vv[bb].x + wv3.y*vv[bb].y + wv3.z*vv[bb].z + wv3.w*vv[bb].w;
                }
            }

            // cross-wave K reduction: waves 2,3 park partials; waves 0,1 fold in
            if (w >= 2) {
#pragma unroll
                for (int bb = 0; bb < 4; ++bb) {
                    float4 v = make_float4(acc[bb][0], acc[bb][1], acc[bb][2], acc[bb][3]);
                    *(float4*)&red[((w - 2) * Bc + bbase + bb) * NROW + rbase] = v;
                }
            }
            __syncthreads();
            if (w < 2) {
#pragma unroll
                for (int bb = 0; bb < 4; ++bb) {
                    float4 p = *(float4*)&red[(w * Bc + bbase + bb) * NROW + rbase];
                    p.x += acc[bb][0]; p.y += acc[bb][1]; p.z += acc[bb][2]; p.w += acc[bb][3];
                    *(float4*)&red[(w * Bc + bbase + bb) * NROW + rbase] = p;
                }
            }
            __syncthreads();

            // elementwise LSTM cell for (cb, j0+cjj); c persistent in register
            {
                float gv[4];
#pragma unroll
                for (int g = 0; g < 4; ++g) {
                    const int r = g * 4 + cjj;
                    gv[g] = red[cb * NROW + r] + red[(Bc + cb) * NROW + r] + bias4[g];
                }
                const float ig = sigmoidf_fast(gv[0]);
                const float fg = sigmoidf_fast(gv[1]);
                const float gg = tanhf(gv[2]);
                const float og = sigmoidf_fast(gv[3]);
                cstate = fg * cstate + ig * gg;
                const float hv = og * tanhf(cstate);
                float* hb = isL1 ? (h2buf + (size_t)((s - 1) & 1) * Bc * Hc)
                                 : (h1buf + (size_t)(s & 1) * Bc * Hc);
                hb[cb * Hc + j0 + cjj] = hv;
            }
        }
        grid_barrier(bar);
    }

    // ---- final FC: out[b, :] = h2[511][b, :] @ fc_w^T + fc_b ; WG b in [0,64) ----
    if (wg < Bc) {
        const int b = wg;
        const float* h2 = h2buf + (size_t)((Sc - 1) & 1) * Bc * Hc + (size_t)b * Hc;
        for (int o = tid; o < OUTc; o += NTHR) {
            float a = fcb[o];
            const float* wr = fcw + (size_t)o * Hc;
            for (int k = 0; k < Hc; k += 4) {
                const float4 hv = *(const float4*)(h2 + k);
                const float4 wv = *(const float4*)(wr + k);
                a += hv.x*wv.x + hv.y*wv.y + hv.z*wv.z + hv.w*wv.w;
            }
            out[b * OUTc + o] = a;
        }
    }
}

extern "C" void kernel_launch(void* const* d_in, const int* in_sizes, int n_in,
                              void* d_out, int out_size, void* d_ws, size_t ws_size,
                              hipStream_t stream) {
    const float* x    = (const float*)d_in[0];
    const float* Wih0 = (const float*)d_in[1];
    const float* Whh0 = (const float*)d_in[2];
    const float* bih0 = (const float*)d_in[3];
    const float* bhh0 = (const float*)d_in[4];
    const float* Wih1 = (const float*)d_in[5];
    const float* Whh1 = (const float*)d_in[6];
    const float* bih1 = (const float*)d_in[7];
    const float* bhh1 = (const float*)d_in[8];
    const float* fcw  = (const float*)d_in[9];
    const float* fcb  = (const float*)d_in[10];
    float* out = (float*)d_out;
    float* wsf = (float*)d_ws;

    // zero barrier counters + h double-buffers (h[-1] = c[-1] = 0 initial state)
    hipMemsetAsync(d_ws, 0, WS_BYTES, stream);

    lstm_persist<<<dim3(NWG), dim3(NTHR), 0, stream>>>(
        x, Wih0, Whh0, bih0, bhh0, Wih1, Whh1, bih1, bhh1, fcw, fcb, out, wsf);
}

// Round 2
// 12630.870 us; speedup vs baseline: 1.7813x; 1.7813x over previous
//
#include <hip/hip_runtime.h>
#include <cmath>

// Problem constants
#define Bc   64
#define Sc   512
#define Dc   256
#define Hc   512
#define OUTc 128

// Kernel config
#define NWG  256   // 128 layer0 + 128 layer1 workgroups (1/CU, all resident)
#define NTHR 512   // 8 waves -> 2 waves/SIMD for latency hiding
#define NL0  128
#define JPW  4     // h indices owned per WG
#define NROW 16    // 4 gates * JPW
#define KP   1028  // padded LDS weight row stride (max K 1024 + 4): 4-row groups land on banks {0,16} -> free 2-way

// h buffers live in ws in transposed-chunked layout: h[k/2][b][2] (float pairs),
// so agent-scope (sc1) loads/stores are lane-contiguous and coalescer-mergeable.
#define HBUF (Bc * Hc)             // 32768 floats per buffer
#define H1_OFF 1024                // float offset of h1 double buffer (byte 4096; bar counter at byte 0)
#define H2_OFF (1024 + 2 * HBUF)
#define WS_BYTES ((H2_OFF + 2 * HBUF) * 4)

// ---- coherent accessors: relaxed agent-scope atomics -> global_load/store sc1,
// ---- L2-bypass to MALL, NO buffer_wbl2/buffer_inv (the round-1 killer). ----
__device__ __forceinline__ float2 cload2(const float* p) {
    unsigned long long u = __hip_atomic_load((const unsigned long long*)p,
                                             __ATOMIC_RELAXED, __HIP_MEMORY_SCOPE_AGENT);
    union { unsigned long long u; float2 f; } c; c.u = u; return c.f;
}
__device__ __forceinline__ void cstore1(float* p, float v) {
    union { float f; unsigned u; } c; c.f = v;
    __hip_atomic_store((unsigned*)p, c.u, __ATOMIC_RELAXED, __HIP_MEMORY_SCOPE_AGENT);
}

// Monotonic-count grid barrier: no reset, no generation flag, no fences.
// Ordering: compiler emits s_waitcnt vmcnt(0) before s_barrier, so every wave's
// sc1 stores are at the MALL before tid0 publishes the arrival.
__device__ __forceinline__ void grid_barrier(unsigned* cnt, unsigned target) {
    __syncthreads();
    if (threadIdx.x == 0) {
        __hip_atomic_fetch_add(cnt, 1u, __ATOMIC_RELAXED, __HIP_MEMORY_SCOPE_AGENT);
        while (__hip_atomic_load(cnt, __ATOMIC_RELAXED, __HIP_MEMORY_SCOPE_AGENT) < target)
            __builtin_amdgcn_s_sleep(2);
    }
    __syncthreads();
}

__device__ __forceinline__ float sigmoidf_fast(float v) {
    return 1.0f / (1.0f + __expf(-v));
}

extern "C" __global__ void __launch_bounds__(NTHR)
lstm_persist(const float* __restrict__ x,
             const float* __restrict__ Wih0, const float* __restrict__ Whh0,
             const float* __restrict__ bih0, const float* __restrict__ bhh0,
             const float* __restrict__ Wih1, const float* __restrict__ Whh1,
             const float* __restrict__ bih1, const float* __restrict__ bhh1,
             const float* __restrict__ fcw, const float* __restrict__ fcb,
             float* __restrict__ out, float* __restrict__ wsf)
{
    __shared__ float Wl[NROW * KP];        // 65.8 KB, resident all steps
    __shared__ float red[4 * Bc * 20];     // 20.5 KB, 4 K-slab partials, stride 20 avoids conflicts

    unsigned* bar = (unsigned*)wsf;
    float* h1b = wsf + H1_OFF;             // [2][HBUF] transposed-chunked
    float* h2b = wsf + H2_OFF;

    const int wg  = blockIdx.x;
    const int tid = threadIdx.x;
    const bool isL1 = (wg >= NL0);
    const int j0 = (isL1 ? wg - NL0 : wg) * JPW;
    const int K  = isL1 ? 1024 : 768;
    const int KD = isL1 ? 512  : 256;      // input-part / recurrent-part boundary

    // ---- one-time weight staging (W_ih || W_hh rows for our 16 gate rows) ----
    {
        const float* Wi = isL1 ? Wih1 : Wih0;
        const float* Wh = isL1 ? Whh1 : Whh0;
        for (int r = 0; r < NROW; ++r) {
            const int g = r >> 2, jj = r & 3;
            const int row = g * Hc + j0 + jj;
            for (int c = tid; c < K; c += NTHR)
                Wl[r * KP + c] = (c < KD) ? Wi[row * KD + c] : Wh[row * Hc + (c - KD)];
        }
    }
    __syncthreads();

    // ---- GEMM tiling: 8 waves split K; lane -> 4 consecutive-b groups x 4 rows ----
    const int w     = tid >> 6;
    const int lane  = tid & 63;
    const int bgrp  = lane & 15;            // b = bgrp + 16*bb  (lane-contiguous b!)
    const int rbase = (lane >> 4) << 2;
    const int KQ    = K >> 3;               // 96 / 128
    const int k0    = w * KQ;
    const int kend  = k0 + KQ;

    const float* wr0 = &Wl[(rbase + 0) * KP];
    const float* wr1 = &Wl[(rbase + 1) * KP];
    const float* wr2 = &Wl[(rbase + 2) * KP];
    const float* wr3 = &Wl[(rbase + 3) * KP];

    // ---- cell mapping: first 256 threads, tid -> (b = tid>>2, jj = tid&3) ----
    const int cb  = tid >> 2;
    const int cjj = tid & 3;
    const int hoff = ((j0 >> 1) + (cjj >> 1)) * 128 + cb * 2 + (cjj & 1); // transposed-chunk offset
    float cstate = 0.0f;
    float bias4[4];
    {
        const float* bi = isL1 ? bih1 : bih0;
        const float* bh = isL1 ? bhh1 : bhh0;
#pragma unroll
        for (int g = 0; g < 4; ++g)
            bias4[g] = bi[g * Hc + j0 + cjj] + bh[g * Hc + j0 + cjj];
    }

    for (int s = 0; s <= Sc; ++s) {
        const bool active = isL1 ? (s >= 1) : (s < Sc);
        if (active) {
            const int t = isL1 ? (s - 1) : s;
            const float* hin = isL1 ? (h1b + (size_t)((s - 1) & 1) * HBUF) : nullptr; // L1 input part
            const float* hrc = isL1 ? (h2b + (size_t)(s & 1) * HBUF)                  // h2[s-2]
                                    : (h1b + (size_t)((s - 1) & 1) * HBUF);           // h1[s-1]
            const float* xb[4]; const float* hinb[4]; const float* hrcb[4];
#pragma unroll
            for (int bb = 0; bb < 4; ++bb) {
                const int b = bgrp + 16 * bb;
                xb[bb]   = x + (size_t)b * Sc * Dc + (size_t)t * Dc;
                hinb[bb] = isL1 ? (hin + b * 2) : nullptr;
                hrcb[bb] = hrc + b * 2;
            }

            float acc[4][4];
#pragma unroll
            for (int i = 0; i < 4; ++i)
#pragma unroll
                for (int j = 0; j < 4; ++j) acc[i][j] = 0.0f;

            // chunk-8 loader: fills va (k..k+3) / vb (k+4..k+7) for all 4 b-groups
            auto loadchunk = [&](int kc, float4* va, float4* vb) {
                if (kc < KD) {
                    if (!isL1) {
#pragma unroll
                        for (int bb = 0; bb < 4; ++bb) {
                            va[bb] = *(const float4*)(xb[bb] + kc);      // x: read-only, normal cached
                            vb[bb] = *(const float4*)(xb[bb] + kc + 4);
                        }
                    } else {
                        const int c2 = kc >> 1;
#pragma unroll
                        for (int bb = 0; bb < 4; ++bb) {
                            float2 p0 = cload2(hinb[bb] + (size_t)(c2 + 0) * 128);
                            float2 p1 = cload2(hinb[bb] + (size_t)(c2 + 1) * 128);
                            float2 p2 = cload2(hinb[bb] + (size_t)(c2 + 2) * 128);
                            float2 p3 = cload2(hinb[bb] + (size_t)(c2 + 3) * 128);
                            va[bb] = make_float4(p0.x, p0.y, p1.x, p1.y);
                            vb[bb] = make_float4(p2.x, p2.y, p3.x, p3.y);
                        }
                    }
                } else {
                    const int c2 = (kc - KD) >> 1;
#pragma unroll
                    for (int bb = 0; bb < 4; ++bb) {
                        float2 p0 = cload2(hrcb[bb] + (size_t)(c2 + 0) * 128);
                        float2 p1 = cload2(hrcb[bb] + (size_t)(c2 + 1) * 128);
                        float2 p2 = cload2(hrcb[bb] + (size_t)(c2 + 2) * 128);
                        float2 p3 = cload2(hrcb[bb] + (size_t)(c2 + 3) * 128);
                        va[bb] = make_float4(p0.x, p0.y, p1.x, p1.y);
                        vb[bb] = make_float4(p2.x, p2.y, p3.x, p3.y);
                    }
                }
            };

            float4 va[4], vb[4], na[4], nb[4];
            loadchunk(k0, va, vb);
            for (int kc = k0; kc < kend; kc += 8) {
                const int kn = (kc + 8 < kend) ? kc + 8 : k0;   // distance-1 prefetch (clamp harmless)
                loadchunk(kn, na, nb);

                const float4 wa0 = *(const float4*)(wr0 + kc), wb0 = *(const float4*)(wr0 + kc + 4);
                const float4 wa1 = *(const float4*)(wr1 + kc), wb1 = *(const float4*)(wr1 + kc + 4);
                const float4 wa2 = *(const float4*)(wr2 + kc), wb2 = *(const float4*)(wr2 + kc + 4);
                const float4 wa3 = *(const float4*)(wr3 + kc), wb3 = *(const float4*)(wr3 + kc + 4);
#pragma unroll
                for (int bb = 0; bb < 4; ++bb) {
                    const float4 A = va[bb], Bv = vb[bb];
                    acc[bb][0] += wa0.x*A.x + wa0.y*A.y + wa0.z*A.z + wa0.w*A.w
                                + wb0.x*Bv.x + wb0.y*Bv.y + wb0.z*Bv.z + wb0.w*Bv.w;
                    acc[bb][1] += wa1.x*A.x + wa1.y*A.y + wa1.z*A.z + wa1.w*A.w
                                + wb1.x*Bv.x + wb1.y*Bv.y + wb1.z*Bv.z + wb1.w*Bv.w;
                    acc[bb][2] += wa2.x*A.x + wa2.y*A.y + wa2.z*A.z + wa2.w*A.w
                                + wb2.x*Bv.x + wb2.y*Bv.y + wb2.z*Bv.z + wb2.w*Bv.w;
                    acc[bb][3] += wa3.x*A.x + wa3.y*A.y + wa3.z*A.z + wa3.w*A.w
                                + wb3.x*Bv.x + wb3.y*Bv.y + wb3.z*Bv.z + wb3.w*Bv.w;
                }
#pragma unroll
                for (int bb = 0; bb < 4; ++bb) { va[bb] = na[bb]; vb[bb] = nb[bb]; }
            }

            // K reduction: waves 4-7 park into slabs, waves 0-3 fold, cell sums 4 slabs
            if (w >= 4) {
#pragma unroll
                for (int bb = 0; bb < 4; ++bb) {
                    const int b = bgrp + 16 * bb;
                    *(float4*)&red[((w - 4) * Bc + b) * 20 + rbase] =
                        make_float4(acc[bb][0], acc[bb][1], acc[bb][2], acc[bb][3]);
                }
            }
            __syncthreads();
            if (w < 4) {
#pragma unroll
                for (int bb = 0; bb < 4; ++bb) {
                    const int b = bgrp + 16 * bb;
                    float4 p = *(float4*)&red[(w * Bc + b) * 20 + rbase];
                    p.x += acc[bb][0]; p.y += acc[bb][1]; p.z += acc[bb][2]; p.w += acc[bb][3];
                    *(float4*)&red[(w * Bc + b) * 20 + rbase] = p;
                }
            }
            __syncthreads();

            if (tid < 256) {
                float gv[4];
#pragma unroll
                for (int g = 0; g < 4; ++g) {
                    const int r = g * 4 + cjj;
                    gv[g] = red[(0 * Bc + cb) * 20 + r] + red[(1 * Bc + cb) * 20 + r]
                          + red[(2 * Bc + cb) * 20 + r] + red[(3 * Bc + cb) * 20 + r] + bias4[g];
                }
                const float ig = sigmoidf_fast(gv[0]);
                const float fg = sigmoidf_fast(gv[1]);
                const float gg = tanhf(gv[2]);
                const float og = sigmoidf_fast(gv[3]);
                cstate = fg * cstate + ig * gg;
                const float hv = og * tanhf(cstate);
                float* hb = isL1 ? (h2b + (size_t)((s - 1) & 1) * HBUF)
                                 : (h1b + (size_t)(s & 1) * HBUF);
                cstore1(hb + hoff, hv);   // coherent write-through; fully lane-coalesced
            }
        }
        grid_barrier(bar, (unsigned)((s + 1) * NWG));
    }

    // ---- FC epilogue: WG b in [0,64); 4-way K split across thread quarters ----
    if (wg < Bc) {
        const int b = wg;
        const float* h2 = h2b + (size_t)((Sc - 1) & 1) * HBUF;
        const int o = tid & 127, q = tid >> 7;
        const float* wrow = fcw + (size_t)o * Hc;
        float a = 0.0f;
        for (int k = q * 128; k < q * 128 + 128; k += 2) {
            const float2 hv = cload2(h2 + (size_t)(k >> 1) * 128 + b * 2);
            a += hv.x * wrow[k] + hv.y * wrow[k + 1];
        }
        red[q * 128 + o] = a;
        __syncthreads();
        if (tid < OUTc)
            out[b * OUTc + tid] = red[tid] + red[128 + tid] + red[256 + tid] + red[384 + tid] + fcb[tid];
    }
}

extern "C" void kernel_launch(void* const* d_in, const int* in_sizes, int n_in,
                              void* d_out, int out_size, void* d_ws, size_t ws_size,
                              hipStream_t stream) {
    const float* x    = (const float*)d_in[0];
    const float* Wih0 = (const float*)d_in[1];
    const float* Whh0 = (const float*)d_in[2];
    const float* bih0 = (const float*)d_in[3];
    const float* bhh0 = (const float*)d_in[4];
    const float* Wih1 = (const float*)d_in[5];
    const float* Whh1 = (const float*)d_in[6];
    const float* bih1 = (const float*)d_in[7];
    const float* bhh1 = (const float*)d_in[8];
    const float* fcw  = (const float*)d_in[9];
    const float* fcb  = (const float*)d_in[10];
    float* out = (float*)d_out;
    float* wsf = (float*)d_ws;

    // zero barrier counter + h buffers (h[-1] = 0 initial state)
    hipMemsetAsync(d_ws, 0, WS_BYTES, stream);

    lstm_persist<<<dim3(NWG), dim3(NTHR), 0, stream>>>(
        x, Wih0, Whh0, bih0, bhh0, Wih1, Whh1, bih1, bhh1, fcw, fcb, out, wsf);
}